// Round 1
// baseline (1050.740 us; speedup 1.0000x reference)
//
#include <hip/hip_runtime.h>
#include <math.h>

#define B_    8
#define CIN   64
#define COUT  128
#define H_    130
#define NPIX  (H_*H_)          // 16900
#define PER_CH (B_*NPIX)       // 135200

// ---------------- Kernel 1: BatchNorm batch statistics -> affine a,b ----------
__global__ __launch_bounds__(256) void bn_stats_kernel(
    const float* __restrict__ x,
    const float* __restrict__ gamma,
    const float* __restrict__ beta,
    float* __restrict__ abuf,
    float* __restrict__ bbuf)
{
    __shared__ float s1[256];
    __shared__ float s2[256];
    const int c   = blockIdx.x;
    const int tid = threadIdx.x;
    float sum = 0.f, sumsq = 0.f;
    for (int b = 0; b < B_; ++b) {
        const float* base = x + ((size_t)b*CIN + c) * NPIX;
        for (int p = tid; p < NPIX; p += 256) {
            float v = base[p];
            sum   += v;
            sumsq += v*v;
        }
    }
    s1[tid] = sum; s2[tid] = sumsq;
    __syncthreads();
    for (int off = 128; off > 0; off >>= 1) {
        if (tid < off) { s1[tid] += s1[tid+off]; s2[tid] += s2[tid+off]; }
        __syncthreads();
    }
    if (tid == 0) {
        float mean = s1[0] * (1.0f/(float)PER_CH);
        float var  = s2[0] * (1.0f/(float)PER_CH) - mean*mean;
        float a = gamma[c] / sqrtf(var + 1e-4f);
        abuf[c] = a;
        bbuf[c] = beta[c] - mean * a;
    }
}

// -------- Kernel 2: fused BN-apply + bin_active + col2im (collapsed form) -----
// img[b,c,y,x] = sign(xbn) * count_i(y) * sum_{valid j} Wsum[j][(x-j)>>4] / 16
// One wave per (b,c,y) row.
__global__ __launch_bounds__(64) void binfold_kernel(
    const float* __restrict__ x,
    const float* __restrict__ abuf,
    const float* __restrict__ bbuf,
    float* __restrict__ img)
{
    const int y = blockIdx.x;
    const int c = blockIdx.y;
    const int b = blockIdx.z;
    const int tid = threadIdx.x;   // 0..63

    __shared__ float absrow[130];
    __shared__ float wsum[3][8];

    const float a  = abuf[c];
    const float bb = bbuf[c];
    const float* row = x + (((size_t)b*CIN + c)*H_ + y) * H_;

    float v0 = a * row[tid]      + bb;          // x = tid        (0..63)
    float v1 = a * row[tid + 64] + bb;          // x = tid+64     (64..127)
    float v2 = 0.f;
    if (tid < 2) v2 = a * row[tid + 128] + bb;  // x = 128,129

    absrow[tid]      = fabsf(v0);
    absrow[tid + 64] = fabsf(v1);
    if (tid < 2) absrow[tid + 128] = fabsf(v2);
    __syncthreads();

    if (tid < 24) {
        int j  = tid >> 3;        // 0..2
        int bx = tid & 7;         // 0..7
        int s  = j + bx*16;       // window start, max 114 -> covers cols..129
        float acc = 0.f;
        #pragma unroll
        for (int t = 0; t < 16; ++t) acc += absrow[s + t];
        wsum[j][bx] = acc;
    }
    __syncthreads();

    const float county = (float)min(min(y + 1, 3), H_ - y);
    float* orow = img + (((size_t)b*CIN + c)*H_ + y) * H_;

    #pragma unroll
    for (int rep = 0; rep < 3; ++rep) {
        int xp = tid + rep*64;
        if (xp < H_) {
            float v = (rep == 0) ? v0 : (rep == 1) ? v1 : v2;
            float sgn = (v > 0.f) ? 1.f : ((v < 0.f) ? -1.f : 0.f);
            float sum = 0.f;
            #pragma unroll
            for (int j = 0; j < 3; ++j) {
                int ox = xp - j;
                if ((unsigned)ox < 128u) sum += wsum[j][ox >> 4];
            }
            orow[xp] = sgn * county * sum * 0.0625f;
        }
    }
}

// ---------------- Kernel 3: direct 3x3 conv (pad=1) + bias + ReLU -------------
// Block: 256 threads = 32 co (tid&31) x 8 x-groups (tid>>5), each thread 17 x.
// Grid: (4 co-groups, 130 y, 8 b). LDS: 16-ci img slab + transposed weights.
#define XT 17
__global__ __launch_bounds__(256) void conv_kernel(
    const float* __restrict__ img,
    const float* __restrict__ w,
    const float* __restrict__ bias,
    float* __restrict__ out)
{
    __shared__ float simg[16*3*132];   // [ci_l][dy][xx], xx 0..131 <-> gx -1..130
    __shared__ float sw[144*33];       // [(ci_l*9+kk)] stride 33, last idx co_l

    const int cog = blockIdx.x;   // 0..3
    const int y   = blockIdx.y;   // 0..129
    const int b   = blockIdx.z;   // 0..7
    const int tid = threadIdx.x;
    const int co_l = tid & 31;
    const int xg   = tid >> 5;
    const int xbase = xg * XT;    // 0,17,...,119

    float acc[XT];
    #pragma unroll
    for (int t = 0; t < XT; ++t) acc[t] = 0.f;

    for (int cc = 0; cc < 4; ++cc) {          // ci chunks of 16
        // ---- stage img slab: 16 ci x 3 rows x 132 (zero-padded borders)
        for (int idx = tid; idx < 16*3*132; idx += 256) {
            int ci_l = idx / 396;
            int r    = idx - ci_l*396;
            int dy   = r / 132;
            int xx   = r - dy*132;
            int gx   = xx - 1;
            int yy   = y + dy - 1;
            float v = 0.f;
            if ((unsigned)gx < (unsigned)H_ && (unsigned)yy < (unsigned)H_)
                v = img[(((size_t)b*CIN + (cc*16 + ci_l))*H_ + yy)*H_ + gx];
            simg[idx] = v;
        }
        // ---- stage weights (coalesced 144-float runs per co), transposed in LDS
        #pragma unroll
        for (int k = 0; k < 18; ++k) {        // 18*256 = 4608
            int idx = tid + k*256;
            int cw  = idx / 144;              // 0..31
            int m   = idx - cw*144;           // ci_l*9 + kk
            sw[m*33 + cw] = w[((size_t)(cog*32 + cw))*576 + cc*144 + m];
        }
        __syncthreads();

        #pragma unroll 1
        for (int ci_l = 0; ci_l < 16; ++ci_l) {
            #pragma unroll
            for (int dy = 0; dy < 3; ++dy) {
                const float* rowp = &simg[(ci_l*3 + dy)*132];
                float win[XT + 2];
                #pragma unroll
                for (int t = 0; t < XT + 2; ++t) {
                    int ix = xbase + t;
                    win[t] = rowp[min(ix, 131)];   // clamp only hits discarded lanes (xg=7)
                }
                const int wb = (ci_l*9 + dy*3) * 33 + co_l;
                float w0 = sw[wb];
                float w1 = sw[wb + 33];
                float w2 = sw[wb + 66];
                #pragma unroll
                for (int t = 0; t < XT; ++t)
                    acc[t] += win[t]*w0 + win[t+1]*w1 + win[t+2]*w2;
            }
        }
        __syncthreads();
    }

    const int co = cog*32 + co_l;
    const float bv = bias[co];
    float* orow = out + (((size_t)b*COUT + co)*H_ + y)*H_;
    #pragma unroll
    for (int t = 0; t < XT; ++t) {
        int xs = xbase + t;
        if (xs < H_) {
            float v = acc[t] + bv;
            orow[xs] = v > 0.f ? v : 0.f;
        }
    }
}

// ------------------------------------------------------------------------------
extern "C" void kernel_launch(void* const* d_in, const int* in_sizes, int n_in,
                              void* d_out, int out_size, void* d_ws, size_t ws_size,
                              hipStream_t stream)
{
    const float* x      = (const float*)d_in[0];
    const float* gamma  = (const float*)d_in[1];
    const float* beta   = (const float*)d_in[2];
    const float* conv_w = (const float*)d_in[3];
    const float* conv_b = (const float*)d_in[4];
    float* out = (float*)d_out;

    float* abuf = (float*)d_ws;       // 64
    float* bbuf = abuf + 64;          // 64
    float* img  = abuf + 128;         // 8*64*130*130 fp32 = 34.6 MB

    bn_stats_kernel<<<64, 256, 0, stream>>>(x, gamma, beta, abuf, bbuf);
    binfold_kernel<<<dim3(H_, CIN, B_), 64, 0, stream>>>(x, abuf, bbuf, img);
    conv_kernel<<<dim3(4, H_, B_), 256, 0, stream>>>(img, conv_w, conv_b, out);
}

// Round 2
// 242.941 us; speedup vs baseline: 4.3251x; 4.3251x over previous
//
#include <hip/hip_runtime.h>
#include <math.h>

#define B_    8
#define CIN   64
#define COUT  128
#define H_    130
#define NPIX  (H_*H_)            // 16900
#define NPX   (B_*NPIX)          // 135200 flat pixels
#define IMW   132                // padded img width/height (zero ring)

typedef __attribute__((ext_vector_type(8))) short short8;   // 8 bf16 (A/B frag)
typedef __attribute__((ext_vector_type(4))) float f32x4;    // MFMA acc

__device__ __forceinline__ ushort f2bf(float f) {
    uint u = __builtin_bit_cast(uint, f);
    uint r = (u + 0x7FFFu + ((u >> 16) & 1u)) >> 16;
    return (ushort)r;
}

// ---------------- BN stage 1: per-(c,b) plane partial sum/sumsq ---------------
__global__ __launch_bounds__(256) void bn_stage1(
    const float* __restrict__ x, float* __restrict__ part)
{
    const int c = blockIdx.x, b = blockIdx.y, tid = threadIdx.x;
    const float4* p = (const float4*)(x + ((size_t)b*CIN + c)*NPIX);
    float s = 0.f, q = 0.f;
    for (int i = tid; i < NPIX/4; i += 256) {   // 16900/4 = 4225 exactly
        float4 v = p[i];
        s += v.x + v.y + v.z + v.w;
        q += v.x*v.x + v.y*v.y + v.z*v.z + v.w*v.w;
    }
    #pragma unroll
    for (int off = 32; off; off >>= 1) { s += __shfl_down(s, off); q += __shfl_down(q, off); }
    __shared__ float ss[4], qq[4];
    if ((tid & 63) == 0) { ss[tid >> 6] = s; qq[tid >> 6] = q; }
    __syncthreads();
    if (tid == 0) {
        s = ss[0] + ss[1] + ss[2] + ss[3];
        q = qq[0] + qq[1] + qq[2] + qq[3];
        part[(c*B_ + b)*2]     = s;
        part[(c*B_ + b)*2 + 1] = q;
    }
}

// ---------------- BN stage 2: combine -> affine a,b ---------------------------
__global__ void bn_stage2(
    const float* __restrict__ part, const float* __restrict__ gamma,
    const float* __restrict__ beta, float* __restrict__ abuf, float* __restrict__ bbuf)
{
    int c = threadIdx.x;                         // 64 threads
    float s = 0.f, q = 0.f;
    for (int b = 0; b < B_; ++b) { s += part[(c*B_+b)*2]; q += part[(c*B_+b)*2+1]; }
    float mean = s * (1.0f/(float)NPX*0.f + 1.0f/135200.f);
    float var  = q * (1.0f/135200.f) - mean*mean;
    float a = gamma[c] / sqrtf(var + 1e-4f);
    abuf[c] = a;
    bbuf[c] = beta[c] - mean * a;
}

// ---------------- weight prep: [co][ci][3][3] f32 -> [co][dydx][ci] bf16 ------
__global__ __launch_bounds__(256) void wprep(
    const float* __restrict__ w, ushort* __restrict__ wT)
{
    int i = blockIdx.x*256 + threadIdx.x;        // 288*256 = 73728 = 128*576
    int co = i / 576, k = i - co*576;
    int dydx = k >> 6, ci = k & 63;
    wT[i] = f2bf(w[co*576 + ci*9 + dydx]);
}

// -------- binfold: BN-apply + bin_active + col2im, channels-last bf16 out -----
// img layout: [b][132][132][64] bf16, zero border ring (pre-memset).
__global__ __launch_bounds__(256) void binfold(
    const float* __restrict__ x, const float* __restrict__ abuf,
    const float* __restrict__ bbuf, ushort* __restrict__ img)
{
    __shared__ ushort tile[H_*66];       // [x][ci], ci stride 66 (pad, 16B-ish safe)
    __shared__ float absrow[4][132];
    __shared__ float wsum[4][24];
    const int y = blockIdx.x, b = blockIdx.y;
    const int tid = threadIdx.x, wv = tid >> 6, lane = tid & 63;
    const float county = (float)min(min(y + 1, 3), H_ - y);

    for (int it = 0; it < 16; ++it) {
        const int ci = wv*16 + it;
        const float* row = x + (((size_t)b*CIN + ci)*H_ + y)*H_;
        const float a = abuf[ci], bb = bbuf[ci];
        float v0 = a*row[lane]      + bb;
        float v1 = a*row[lane + 64] + bb;
        float v2 = 0.f;
        if (lane < 2) v2 = a*row[lane + 128] + bb;
        absrow[wv][lane]      = fabsf(v0);
        absrow[wv][lane + 64] = fabsf(v1);
        if (lane < 2) absrow[wv][lane + 128] = fabsf(v2);
        __syncthreads();
        if (lane < 24) {
            int j = lane >> 3, bx = lane & 7;
            int s = j + bx*16;
            float acc = 0.f;
            #pragma unroll
            for (int t = 0; t < 16; ++t) acc += absrow[wv][s + t];
            wsum[wv][j*8 + bx] = acc;
        }
        __syncthreads();
        #pragma unroll
        for (int rep = 0; rep < 3; ++rep) {
            int xp = lane + rep*64;
            if (xp < H_) {
                float v = (rep == 0) ? v0 : (rep == 1) ? v1 : v2;
                float sgn = (v > 0.f) ? 1.f : ((v < 0.f) ? -1.f : 0.f);
                float sum = 0.f;
                #pragma unroll
                for (int j = 0; j < 3; ++j) {
                    int ox = xp - j;
                    if ((unsigned)ox < 128u) sum += wsum[wv][j*8 + (ox >> 4)];
                }
                tile[xp*66 + ci] = f2bf(sgn * county * sum * 0.0625f);
            }
        }
        __syncthreads();
    }
    // coalesced channels-last store: img[b][y+1][x+1][ci]
    const int base = ((b*IMW + y + 1)*IMW + 1)*32;   // uint index
    uint* imgU = (uint*)img;
    const uint* tU = (const uint*)tile;
    for (int i = tid; i < H_*32; i += 256) {
        int xp = i >> 5, cp = i & 31;
        imgU[base + xp*32 + cp] = tU[xp*33 + cp];
    }
}

// ---------------- conv: implicit-GEMM bf16 MFMA 16x16x32 ----------------------
// C[co][px] : M=co(128), N=px(128/block), K=576 (dydx*64+ci).
// A = wT[co][dydx][ci] (lane m=co, k contig) ; B = img CL (lane n=px, k contig).
// D: col=lane&15=px (coalesced NCHW store), row=quad*4+r=co.
__global__ __launch_bounds__(256) void conv_mfma(
    const ushort* __restrict__ img, const ushort* __restrict__ wT,
    const float* __restrict__ bias, float* __restrict__ out)
{
    const int tid  = threadIdx.x;
    const int lane = tid & 63;
    const int wv   = tid >> 6;
    const int l16  = lane & 15;
    const int quad = lane >> 4;
    const int ch   = wv >> 1;       // co half
    const int ph   = wv & 1;        // px half
    const int n0   = blockIdx.x * 128;

    int aIdx[4]; int oBase[4]; int valid[4];
    #pragma unroll
    for (int nt = 0; nt < 4; ++nt) {
        int px = n0 + ph*64 + nt*16 + l16;
        valid[nt] = (px < NPX);
        int pc = valid[nt] ? px : NPX - 1;
        int b = (int)((unsigned)pc / 16900u);
        int r = pc - b*16900;
        int y = (int)((unsigned)r / 130u);
        int x = r - y*130;
        aIdx[nt]  = ((b*IMW + y + 1)*IMW + (x + 1))*64 + quad*8;
        oBase[nt] = b*(COUT*NPIX) + y*H_ + x;
    }
    int wIdx[4];
    #pragma unroll
    for (int mt = 0; mt < 4; ++mt)
        wIdx[mt] = (ch*64 + mt*16 + l16)*576 + quad*8;

    f32x4 acc[4][4];
    #pragma unroll
    for (int mt = 0; mt < 4; ++mt)
        #pragma unroll
        for (int nt = 0; nt < 4; ++nt)
            acc[mt][nt] = (f32x4){0.f, 0.f, 0.f, 0.f};

    #pragma unroll 3
    for (int dydx = 0; dydx < 9; ++dydx) {
        const int dy = (int)((unsigned)dydx / 3u);
        const int dx = dydx - dy*3;
        const int sOff = ((dy - 1)*IMW + (dx - 1))*64;
        #pragma unroll
        for (int h = 0; h < 2; ++h) {
            const int ciOff = h*32;
            short8 af[4], bf[4];
            #pragma unroll
            for (int mt = 0; mt < 4; ++mt)
                af[mt] = *(const short8*)(wT + wIdx[mt] + dydx*64 + ciOff);
            #pragma unroll
            for (int nt = 0; nt < 4; ++nt)
                bf[nt] = *(const short8*)(img + aIdx[nt] + sOff + ciOff);
            #pragma unroll
            for (int mt = 0; mt < 4; ++mt)
                #pragma unroll
                for (int nt = 0; nt < 4; ++nt)
                    acc[mt][nt] = __builtin_amdgcn_mfma_f32_16x16x32_bf16(
                        af[mt], bf[nt], acc[mt][nt], 0, 0, 0);
        }
    }

    #pragma unroll
    for (int mt = 0; mt < 4; ++mt) {
        #pragma unroll
        for (int r = 0; r < 4; ++r) {
            const int co = ch*64 + mt*16 + quad*4 + r;
            const float bv = bias[co];
            #pragma unroll
            for (int nt = 0; nt < 4; ++nt) {
                if (valid[nt]) {
                    float v = acc[mt][nt][r] + bv;
                    out[oBase[nt] + co*NPIX] = v > 0.f ? v : 0.f;
                }
            }
        }
    }
}

// ------------------------------------------------------------------------------
extern "C" void kernel_launch(void* const* d_in, const int* in_sizes, int n_in,
                              void* d_out, int out_size, void* d_ws, size_t ws_size,
                              hipStream_t stream)
{
    const float* x      = (const float*)d_in[0];
    const float* gamma  = (const float*)d_in[1];
    const float* beta   = (const float*)d_in[2];
    const float* conv_w = (const float*)d_in[3];
    const float* conv_b = (const float*)d_in[4];
    float* out = (float*)d_out;

    float*  part = (float*)d_ws;            // 1024 f32
    float*  abuf = part + 1024;             // 64
    float*  bbuf = abuf + 64;               // 64
    ushort* wT   = (ushort*)(bbuf + 64);    // 73728 bf16 (offset 4608 B, 16B aligned)
    ushort* img  = wT + 73728;              // 8*132*132*64 bf16 = 17,842,176 B

    hipMemsetAsync(img, 0, (size_t)B_*IMW*IMW*64*2, stream);
    bn_stage1<<<dim3(CIN, B_), 256, 0, stream>>>(x, part);
    bn_stage2<<<1, 64, 0, stream>>>(part, gamma, beta, abuf, bbuf);
    wprep<<<288, 256, 0, stream>>>(conv_w, wT);
    binfold<<<dim3(H_, B_), 256, 0, stream>>>(x, abuf, bbuf, img);
    conv_mfma<<<(NPX + 127)/128, 256, 0, stream>>>(img, wT, conv_b, out);
}

// Round 3
// 194.586 us; speedup vs baseline: 5.3999x; 1.2485x over previous
//
#include <hip/hip_runtime.h>
#include <math.h>

#define B_    8
#define CIN   64
#define COUT  128
#define H_    130
#define NPIX  (H_*H_)            // 16900
#define NPX   (B_*NPIX)          // 135200 flat pixels
#define IMW   132                // padded img width/height (zero ring)
#define ROWE  (8*IMW*8)          // 8448 elems per (b,yy) row slab

typedef __attribute__((ext_vector_type(8))) short short8;   // 8 bf16 (A/B frag)
typedef __attribute__((ext_vector_type(4))) float f32x4;    // MFMA acc

__device__ __forceinline__ ushort f2bf(float f) {
    uint u = __builtin_bit_cast(uint, f);
    uint r = (u + 0x7FFFu + ((u >> 16) & 1u)) >> 16;
    return (ushort)r;
}

// ---------------- BN stage 1: per-(c,b) plane partial sum/sumsq ---------------
__global__ __launch_bounds__(256) void bn_stage1(
    const float* __restrict__ x, float* __restrict__ part)
{
    const int c = blockIdx.x, b = blockIdx.y, tid = threadIdx.x;
    const float4* p = (const float4*)(x + ((size_t)b*CIN + c)*NPIX);
    float s = 0.f, q = 0.f;
    for (int i = tid; i < NPIX/4; i += 256) {   // 16900/4 = 4225 exactly
        float4 v = p[i];
        s += v.x + v.y + v.z + v.w;
        q += v.x*v.x + v.y*v.y + v.z*v.z + v.w*v.w;
    }
    #pragma unroll
    for (int off = 32; off; off >>= 1) { s += __shfl_down(s, off); q += __shfl_down(q, off); }
    __shared__ float ss[4], qq[4];
    if ((tid & 63) == 0) { ss[tid >> 6] = s; qq[tid >> 6] = q; }
    __syncthreads();
    if (tid == 0) {
        s = ss[0] + ss[1] + ss[2] + ss[3];
        q = qq[0] + qq[1] + qq[2] + qq[3];
        part[(c*B_ + b)*2]     = s;
        part[(c*B_ + b)*2 + 1] = q;
    }
}

// ---------------- BN stage 2: combine -> affine a,b ---------------------------
__global__ void bn_stage2(
    const float* __restrict__ part, const float* __restrict__ gamma,
    const float* __restrict__ beta, float* __restrict__ abuf, float* __restrict__ bbuf)
{
    int c = threadIdx.x;                         // 64 threads
    float s = 0.f, q = 0.f;
    for (int b = 0; b < B_; ++b) { s += part[(c*B_+b)*2]; q += part[(c*B_+b)*2+1]; }
    float mean = s * (1.0f/135200.f);
    float var  = q * (1.0f/135200.f) - mean*mean;
    float a = gamma[c] / sqrtf(var + 1e-4f);
    abuf[c] = a;
    bbuf[c] = beta[c] - mean * a;
}

// ---------------- weight prep: [co][ci][3][3] f32 -> [co][dydx][ci] bf16 ------
__global__ __launch_bounds__(256) void wprep(
    const float* __restrict__ w, ushort* __restrict__ wT)
{
    int i = blockIdx.x*256 + threadIdx.x;        // 288*256 = 73728 = 128*576
    int co = i / 576, k = i - co*576;
    int dydx = k >> 6, ci = k & 63;
    wT[i] = f2bf(w[co*576 + ci*9 + dydx]);
}

// -------- binfold: BN-apply + bin_active + col2im, layout [b][yy][cg][xx][ci8] -
// Zero border ring written here (rows yy=0/131 and columns xx=0/131).
// absrow/wsum are PER-WAVE private: wave-local s_waitcnt ordering, no barriers
// inside the it-loop (4 waves run independently).
__global__ __launch_bounds__(256) void binfold(
    const float* __restrict__ x, const float* __restrict__ abuf,
    const float* __restrict__ bbuf, ushort* __restrict__ img)
{
    __shared__ __align__(16) ushort tile[H_*66];   // [x][ci], ci stride 66
    __shared__ float absrow[4][132];
    __shared__ float wsum[4][24];
    const int yy = blockIdx.x;          // 0..131
    const int b  = blockIdx.y;
    const int tid = threadIdx.x, wv = tid >> 6, lane = tid & 63;
    uint* rowU = (uint*)(img + (size_t)(b*IMW + yy)*ROWE);

    if (yy == 0 || yy == IMW-1) {                  // pure border row
        for (int i = tid; i < ROWE/2; i += 256) rowU[i] = 0u;
        return;
    }
    const int y = yy - 1;
    const float county = (float)min(min(y + 1, 3), H_ - y);

    for (int it = 0; it < 16; ++it) {
        const int ci = wv*16 + it;
        const float* row = x + (((size_t)b*CIN + ci)*H_ + y)*H_;
        const float a = abuf[ci], bb = bbuf[ci];
        float v0 = a*row[lane]      + bb;
        float v1 = a*row[lane + 64] + bb;
        float v2 = 0.f;
        if (lane < 2) v2 = a*row[lane + 128] + bb;
        absrow[wv][lane]      = fabsf(v0);
        absrow[wv][lane + 64] = fabsf(v1);
        if (lane < 2) absrow[wv][lane + 128] = fabsf(v2);
        asm volatile("s_waitcnt lgkmcnt(0)" ::: "memory");
        if (lane < 24) {
            int j = lane >> 3, bx = lane & 7;
            int s = j + bx*16;
            float acc = 0.f;
            #pragma unroll
            for (int t = 0; t < 16; ++t) acc += absrow[wv][s + t];
            wsum[wv][j*8 + bx] = acc;
        }
        asm volatile("s_waitcnt lgkmcnt(0)" ::: "memory");
        #pragma unroll
        for (int rep = 0; rep < 3; ++rep) {
            int xp = lane + rep*64;
            if (xp < H_) {
                float v = (rep == 0) ? v0 : (rep == 1) ? v1 : v2;
                float sgn = (v > 0.f) ? 1.f : ((v < 0.f) ? -1.f : 0.f);
                float sum = 0.f;
                #pragma unroll
                for (int j = 0; j < 3; ++j) {
                    int ox = xp - j;
                    if ((unsigned)ox < 128u) sum += wsum[wv][j*8 + (ox >> 4)];
                }
                tile[xp*66 + ci] = f2bf(sgn * county * sum * 0.0625f);
            }
        }
    }
    __syncthreads();
    // store row slab: [cg(8)][xx(132)][ci8] with zero side columns
    const uint* tU = (const uint*)tile;
    for (int i = tid; i < 8*H_*4; i += 256) {      // 4160 uints
        int cg = (int)((unsigned)i / 520u);
        int r  = i - cg*520;
        int xp = r >> 2, u = r & 3;
        rowU[(cg*IMW + xp + 1)*4 + u] = tU[xp*33 + cg*4 + u];
    }
    if (tid < 64) {
        int cg = tid >> 3, side = (tid >> 2) & 1, u = tid & 3;
        rowU[(cg*IMW + (side ? (IMW-1) : 0))*4 + u] = 0u;
    }
}

// ---------------- conv: implicit-GEMM bf16 MFMA, LDS-staged row slab ----------
// Block = one (b,y) output row. LDS holds img rows yy=y..y+2 (3 contiguous
// slabs). 4 waves = ch(co-half) x ph(px-half); each wave: 4 mt x 5 nf frags.
// nf = ph*4+nt -> nf=4 computed by both ph waves (identical value, benign).
#define LDSE (3*ROWE + 128)
__global__ __launch_bounds__(256, 3) void conv_mfma(
    const ushort* __restrict__ img, const ushort* __restrict__ wT,
    const float* __restrict__ bias, float* __restrict__ out)
{
    __shared__ __align__(16) ushort sB[LDSE];
    const int y = blockIdx.x, b = blockIdx.y;
    const int tid = threadIdx.x, lane = tid & 63, wv = tid >> 6;
    const int l16 = lane & 15, quad = lane >> 4;
    const int ch = wv >> 1, ph = wv & 1;

    // stage 3 contiguous row slabs (50688 B), linear copy
    {
        const uint4* src = (const uint4*)(img + (size_t)(b*IMW + y)*ROWE);
        uint4* dst = (uint4*)sB;
        for (int i = tid; i < 3*ROWE/8; i += 256) dst[i] = src[i];   // 3168
    }
    __syncthreads();

    int wIdx[4];
    #pragma unroll
    for (int mt = 0; mt < 4; ++mt)
        wIdx[mt] = (ch*64 + mt*16 + l16)*576 + quad*8;

    // per-lane invariant LDS offset: cg-part (quad) + x-part (ph,l16)
    const int ldsLane = (quad*IMW + ph*64 + l16)*8;

    f32x4 acc[4][5];
    #pragma unroll
    for (int mt = 0; mt < 4; ++mt)
        #pragma unroll
        for (int nt = 0; nt < 5; ++nt)
            acc[mt][nt] = (f32x4){0.f, 0.f, 0.f, 0.f};

    #pragma unroll 3
    for (int dydx = 0; dydx < 9; ++dydx) {
        const int dy = (int)((unsigned)dydx / 3u);
        const int dx = dydx - dy*3;
        #pragma unroll
        for (int h = 0; h < 2; ++h) {
            short8 af[4], bf[5];
            #pragma unroll
            for (int mt = 0; mt < 4; ++mt)
                af[mt] = *(const short8*)(wT + wIdx[mt] + dydx*64 + h*32);
            const int koff = dy*ROWE + h*4*IMW*8 + dx*8;
            #pragma unroll
            for (int nt = 0; nt < 5; ++nt)
                bf[nt] = *(const short8*)(sB + ldsLane + koff + nt*16*8);
            #pragma unroll
            for (int mt = 0; mt < 4; ++mt)
                #pragma unroll
                for (int nt = 0; nt < 5; ++nt)
                    acc[mt][nt] = __builtin_amdgcn_mfma_f32_16x16x32_bf16(
                        af[mt], bf[nt], acc[mt][nt], 0, 0, 0);
        }
    }

    const size_t ob = (size_t)b*COUT*NPIX + (size_t)y*H_;
    #pragma unroll
    for (int mt = 0; mt < 4; ++mt) {
        #pragma unroll
        for (int r = 0; r < 4; ++r) {
            const int co = ch*64 + mt*16 + quad*4 + r;
            const float bv = bias[co];
            #pragma unroll
            for (int nt = 0; nt < 5; ++nt) {
                int xq = (ph*4 + nt)*16 + l16;
                if (xq < H_) {
                    float v = acc[mt][nt][r] + bv;
                    out[ob + (size_t)co*NPIX + xq] = v > 0.f ? v : 0.f;
                }
            }
        }
    }
}

// ------------------------------------------------------------------------------
extern "C" void kernel_launch(void* const* d_in, const int* in_sizes, int n_in,
                              void* d_out, int out_size, void* d_ws, size_t ws_size,
                              hipStream_t stream)
{
    const float* x      = (const float*)d_in[0];
    const float* gamma  = (const float*)d_in[1];
    const float* beta   = (const float*)d_in[2];
    const float* conv_w = (const float*)d_in[3];
    const float* conv_b = (const float*)d_in[4];
    float* out = (float*)d_out;

    float*  part = (float*)d_ws;            // 1024 f32
    float*  abuf = part + 1024;             // 64
    float*  bbuf = abuf + 64;               // 64
    ushort* wT   = (ushort*)(bbuf + 64);    // 73728 bf16 (byte offset 4608)
    ushort* img  = wT + 73728;              // 8*132*8448 bf16 = 17,842,176 B

    bn_stage1<<<dim3(CIN, B_), 256, 0, stream>>>(x, part);
    bn_stage2<<<1, 64, 0, stream>>>(part, gamma, beta, abuf, bbuf);
    wprep<<<288, 256, 0, stream>>>(conv_w, wT);
    binfold<<<dim3(IMW, B_), 256, 0, stream>>>(x, abuf, bbuf, img);
    conv_mfma<<<dim3(H_, B_), 256, 0, stream>>>(img, wT, conv_b, out);
}

// Round 4
// 184.446 us; speedup vs baseline: 5.6967x; 1.0550x over previous
//
#include <hip/hip_runtime.h>
#include <math.h>

#define B_    8
#define CIN   64
#define COUT  128
#define H_    130
#define NPIX  (H_*H_)            // 16900
#define NPX   (B_*NPIX)          // 135200 flat pixels
#define IMW   132                // padded img width/height (zero ring)
#define ROWE  (8*IMW*8)          // 8448 elems per (b,yy) row slab
#define XXS   82                 // conv LDS xx-stride (328 dw % 32 = 8 -> staggered quads)

typedef __attribute__((ext_vector_type(8))) short short8;   // 8 bf16 (A/B frag)
typedef __attribute__((ext_vector_type(4))) float f32x4;    // MFMA acc

__device__ __forceinline__ ushort f2bf(float f) {
    uint u = __builtin_bit_cast(uint, f);
    uint r = (u + 0x7FFFu + ((u >> 16) & 1u)) >> 16;
    return (ushort)r;
}

// ---------------- BN stage 1: per-(c,b) plane partial sum/sumsq ---------------
__global__ __launch_bounds__(256) void bn_stage1(
    const float* __restrict__ x, float* __restrict__ part)
{
    const int c = blockIdx.x, b = blockIdx.y, tid = threadIdx.x;
    const float4* p = (const float4*)(x + ((size_t)b*CIN + c)*NPIX);
    float s = 0.f, q = 0.f;
    for (int i = tid; i < NPIX/4; i += 256) {   // 16900/4 = 4225 exactly
        float4 v = p[i];
        s += v.x + v.y + v.z + v.w;
        q += v.x*v.x + v.y*v.y + v.z*v.z + v.w*v.w;
    }
    #pragma unroll
    for (int off = 32; off; off >>= 1) { s += __shfl_down(s, off); q += __shfl_down(q, off); }
    __shared__ float ss[4], qq[4];
    if ((tid & 63) == 0) { ss[tid >> 6] = s; qq[tid >> 6] = q; }
    __syncthreads();
    if (tid == 0) {
        s = ss[0] + ss[1] + ss[2] + ss[3];
        q = qq[0] + qq[1] + qq[2] + qq[3];
        part[(c*B_ + b)*2]     = s;
        part[(c*B_ + b)*2 + 1] = q;
    }
}

// ------- fused: weight prep (f32 [co][ci][3][3] -> bf16 [co][dydx][ci]) -------
// ------- + BN stage 2 (combine partials -> affine a,b) on block 0 ------------
__global__ __launch_bounds__(256) void wprep_bn(
    const float* __restrict__ w, const float* __restrict__ part,
    const float* __restrict__ gamma, const float* __restrict__ beta,
    ushort* __restrict__ wT, float* __restrict__ abuf, float* __restrict__ bbuf)
{
    int i = blockIdx.x*256 + threadIdx.x;        // 288*256 = 73728 = 128*576
    int co = i / 576, k = i - co*576;
    int dydx = k >> 6, ci = k & 63;
    wT[i] = f2bf(w[co*576 + ci*9 + dydx]);
    if (blockIdx.x == 0 && threadIdx.x < 64) {
        int c = threadIdx.x;
        float s = 0.f, q = 0.f;
        for (int b = 0; b < B_; ++b) { s += part[(c*B_+b)*2]; q += part[(c*B_+b)*2+1]; }
        float mean = s * (1.0f/135200.f);
        float var  = q * (1.0f/135200.f) - mean*mean;
        float a = gamma[c] / sqrtf(var + 1e-4f);
        abuf[c] = a;
        bbuf[c] = beta[c] - mean * a;
    }
}

// -------- binfold: BN-apply + bin_active + col2im, layout [b][yy][cg][xx][ci8] -
__global__ __launch_bounds__(256) void binfold(
    const float* __restrict__ x, const float* __restrict__ abuf,
    const float* __restrict__ bbuf, ushort* __restrict__ img)
{
    __shared__ __align__(16) ushort tile[H_*66];   // [x][ci], ci stride 66
    __shared__ float absrow[4][132];
    __shared__ float wsum[4][24];
    const int yy = blockIdx.x;          // 0..131
    const int b  = blockIdx.y;
    const int tid = threadIdx.x, wv = tid >> 6, lane = tid & 63;
    uint* rowU = (uint*)(img + (size_t)(b*IMW + yy)*ROWE);

    if (yy == 0 || yy == IMW-1) {                  // pure border row
        for (int i = tid; i < ROWE/2; i += 256) rowU[i] = 0u;
        return;
    }
    const int y = yy - 1;
    const float county = (float)min(min(y + 1, 3), H_ - y);

    for (int it = 0; it < 16; ++it) {
        const int ci = wv*16 + it;
        const float* row = x + (((size_t)b*CIN + ci)*H_ + y)*H_;
        const float a = abuf[ci], bb = bbuf[ci];
        float v0 = a*row[lane]      + bb;
        float v1 = a*row[lane + 64] + bb;
        float v2 = 0.f;
        if (lane < 2) v2 = a*row[lane + 128] + bb;
        absrow[wv][lane]      = fabsf(v0);
        absrow[wv][lane + 64] = fabsf(v1);
        if (lane < 2) absrow[wv][lane + 128] = fabsf(v2);
        asm volatile("s_waitcnt lgkmcnt(0)" ::: "memory");
        if (lane < 24) {
            int j = lane >> 3, bx = lane & 7;
            int s = j + bx*16;
            float acc = 0.f;
            #pragma unroll
            for (int t = 0; t < 16; ++t) acc += absrow[wv][s + t];
            wsum[wv][j*8 + bx] = acc;
        }
        asm volatile("s_waitcnt lgkmcnt(0)" ::: "memory");
        #pragma unroll
        for (int rep = 0; rep < 3; ++rep) {
            int xp = lane + rep*64;
            if (xp < H_) {
                float v = (rep == 0) ? v0 : (rep == 1) ? v1 : v2;
                float sgn = (v > 0.f) ? 1.f : ((v < 0.f) ? -1.f : 0.f);
                float sum = 0.f;
                #pragma unroll
                for (int j = 0; j < 3; ++j) {
                    int ox = xp - j;
                    if ((unsigned)ox < 128u) sum += wsum[wv][j*8 + (ox >> 4)];
                }
                tile[xp*66 + ci] = f2bf(sgn * county * sum * 0.0625f);
            }
        }
    }
    __syncthreads();
    // store row slab: [cg(8)][xx(132)][ci8] with zero side columns
    const uint* tU = (const uint*)tile;
    for (int i = tid; i < 8*H_*4; i += 256) {      // 4160 uints
        int cg = (int)((unsigned)i / 520u);
        int r  = i - cg*520;
        int xp = r >> 2, u = r & 3;
        rowU[(cg*IMW + xp + 1)*4 + u] = tU[xp*33 + cg*4 + u];
    }
    if (tid < 64) {
        int cg = tid >> 3, side = (tid >> 2) & 1, u = tid & 3;
        rowU[(cg*IMW + (side ? (IMW-1) : 0))*4 + u] = 0u;
    }
}

// ---------------- conv: implicit-GEMM bf16 MFMA, half-row blocks --------------
// Block = (xh half-row, y, b). LDS: 3 rows x 8 cg x 82 xx x ci8 (31.5 KB,
// real cols 0..66, 67..81 zero). 4 waves = co-quarters (2 mt x 5 nt each).
__global__ __launch_bounds__(256, 4) void conv_mfma(
    const ushort* __restrict__ img, const ushort* __restrict__ wT,
    const float* __restrict__ bias, float* __restrict__ out)
{
    __shared__ __align__(16) ushort sB[3*8*XXS*8];
    const int xh = blockIdx.x, y = blockIdx.y, b = blockIdx.z;
    const int tid = threadIdx.x, lane = tid & 63, q = tid >> 6;
    const int l16 = lane & 15, quad = lane >> 4;
    const int x0 = xh * 65;

    // ---- stage: 24 runs (dy,cg) x (67 real + 15 zero) uint4 columns
    {
        uint4* s4 = (uint4*)sB;
        const uint4 z = {0u, 0u, 0u, 0u};
        for (int i = tid; i < 24*XXS; i += 256) {          // 1968
            int run = (int)((unsigned)i / (unsigned)XXS);
            int c   = i - run*XXS;
            int dy  = run >> 3, cg = run & 7;
            uint4 v = z;
            if (c < 67)
                v = *(const uint4*)(img + (size_t)(b*IMW + y + dy)*ROWE
                                    + (cg*IMW + x0 + c)*8);
            s4[run*XXS + c] = v;
        }
    }
    __syncthreads();

    int wIdx[2];
    #pragma unroll
    for (int mt = 0; mt < 2; ++mt)
        wIdx[mt] = (q*32 + mt*16 + l16)*576 + quad*8;

    const int bBase = (quad*XXS + l16)*8;   // cg part (h adds 4*XXS*8), x part

    f32x4 acc[2][5];
    #pragma unroll
    for (int mt = 0; mt < 2; ++mt)
        #pragma unroll
        for (int nt = 0; nt < 5; ++nt)
            acc[mt][nt] = (f32x4){0.f, 0.f, 0.f, 0.f};

    #pragma unroll 3
    for (int dydx = 0; dydx < 9; ++dydx) {
        const int dy = (int)((unsigned)dydx / 3u);
        const int dx = dydx - dy*3;
        #pragma unroll
        for (int h = 0; h < 2; ++h) {
            short8 af[2], bf[5];
            #pragma unroll
            for (int mt = 0; mt < 2; ++mt)
                af[mt] = *(const short8*)(wT + wIdx[mt] + dydx*64 + h*32);
            const int ko = ((dy*8 + 4*h)*XXS + dx)*8;
            #pragma unroll
            for (int nt = 0; nt < 5; ++nt)
                bf[nt] = *(const short8*)(sB + bBase + ko + nt*128);
            #pragma unroll
            for (int mt = 0; mt < 2; ++mt)
                #pragma unroll
                for (int nt = 0; nt < 5; ++nt)
                    acc[mt][nt] = __builtin_amdgcn_mfma_f32_16x16x32_bf16(
                        af[mt], bf[nt], acc[mt][nt], 0, 0, 0);
        }
    }

    const size_t ob = (size_t)b*COUT*NPIX + (size_t)y*H_ + x0;
    #pragma unroll
    for (int mt = 0; mt < 2; ++mt) {
        #pragma unroll
        for (int r = 0; r < 4; ++r) {
            const int co = q*32 + mt*16 + quad*4 + r;
            const float bv = bias[co];
            #pragma unroll
            for (int nt = 0; nt < 5; ++nt) {
                int p = nt*16 + l16;
                if (p < 65) {                      // valid px of this half
                    float v = acc[mt][nt][r] + bv;
                    out[ob + (size_t)co*NPIX + p] = v > 0.f ? v : 0.f;
                }
            }
        }
    }
}

// ------------------------------------------------------------------------------
extern "C" void kernel_launch(void* const* d_in, const int* in_sizes, int n_in,
                              void* d_out, int out_size, void* d_ws, size_t ws_size,
                              hipStream_t stream)
{
    const float* x      = (const float*)d_in[0];
    const float* gamma  = (const float*)d_in[1];
    const float* beta   = (const float*)d_in[2];
    const float* conv_w = (const float*)d_in[3];
    const float* conv_b = (const float*)d_in[4];
    float* out = (float*)d_out;

    float*  part = (float*)d_ws;            // 1024 f32
    float*  abuf = part + 1024;             // 64
    float*  bbuf = abuf + 64;               // 64
    ushort* wT   = (ushort*)(bbuf + 64);    // 73728 bf16 (byte offset 4608)
    ushort* img  = wT + 73728;              // 8*132*8448 bf16 = 17,842,176 B

    bn_stage1<<<dim3(CIN, B_), 256, 0, stream>>>(x, part);
    wprep_bn<<<288, 256, 0, stream>>>(conv_w, part, gamma, beta, wT, abuf, bbuf);
    binfold<<<dim3(IMW, B_), 256, 0, stream>>>(x, abuf, bbuf, img);
    conv_mfma<<<dim3(2, H_, B_), 256, 0, stream>>>(img, wT, conv_b, out);
}